// Round 14
// baseline (80.698 us; speedup 1.0000x reference)
//
#include <hip/hip_runtime.h>
#include <math.h>

#define NB 8
#define NS 512
#define NE 32
#define DE 256
#define DH 512
#define DA 200
#define DAP 224   // padded att dim (7 tiles of 32)
#define NJ 7

typedef __bf16 bf16x8 __attribute__((ext_vector_type(8)));
typedef float f32x16 __attribute__((ext_vector_type(16)));

__device__ __forceinline__ float tanh_fast(float x) {
    float e = __expf(x + x);
    return fmaf(-2.f, __builtin_amdgcn_rcpf(e + 1.f), 1.f);
}

// ---- stage 1: partial sums of cxt over s-chunks (512 blocks) ----
__global__ __launch_bounds__(256) void cmean_partial(const float* __restrict__ cxt,
                                                     float* __restrict__ psum) {
    const int g = blockIdx.x;       // b*64 + c
    const int b = g >> 6, c = g & 63;
    const int t = threadIdx.x;
    const float* base = cxt + ((size_t)b * NS + c * 8) * DH;
    float s0 = 0.f, s1 = 0.f;
    #pragma unroll
    for (int s = 0; s < 8; ++s) {
        s0 += base[s * DH + t];
        s1 += base[s * DH + t + 256];
    }
    psum[(size_t)g * DH + t]       = s0;
    psum[(size_t)g * DH + t + 256] = s1;
}

// ---- stage 2: reduce partials -> cmean; hatt[b][a] = cmean @ Wh (zero-padded) ----
__global__ __launch_bounds__(256) void hatt_from_psum(const float* __restrict__ psum,
                                                      const float* __restrict__ Wh,
                                                      float* __restrict__ hattw) {
    const int b = blockIdx.x;
    const int t = threadIdx.x;
    __shared__ float cm[DH];
    float s0 = 0.f, s1 = 0.f;
    for (int c = 0; c < 64; ++c) {
        s0 += psum[((size_t)b * 64 + c) * DH + t];
        s1 += psum[((size_t)b * 64 + c) * DH + t + 256];
    }
    cm[t]       = s0 * (1.f / NS);
    cm[t + 256] = s1 * (1.f / NS);
    __syncthreads();
    if (t < DAP) {
        float acc = 0.f;
        if (t < DA)
            for (int h = 0; h < DH; ++h)
                acc = fmaf(cm[h], Wh[h * DA + t], acc);
        hattw[b * DAP + t] = acc;
    }
}

// ---- stage 3: pack We into bf16 B-fragment layout (zero-padded cols) ----
__global__ __launch_bounds__(64) void wef_build(const float* __restrict__ We,
                                                __bf16* __restrict__ wef) {
    const int f = blockIdx.x;
    const int l = threadIdx.x;
    const int nj = f >> 4, kk = f & 15;
    const int n = nj * 32 + (l & 31);
    bf16x8 v;
    #pragma unroll
    for (int e = 0; e < 8; ++e) {
        int K = kk * 16 + ((l >> 5) << 2) + (e & 3) + 8 * (e >> 2);
        v[e] = (__bf16)((n < DA) ? We[K * DA + n] : 0.f);
    }
    reinterpret_cast<bf16x8*>(wef)[f * 64 + l] = v;
}

// ---- per-tile compute after A is ready ----
__device__ __forceinline__ void compute_tile(const bf16x8 (&A)[16],
                                             const __bf16* __restrict__ wef_lds,
                                             const float* __restrict__ hatt_lds,
                                             const float* __restrict__ ws_lds,
                                             const float* __restrict__ eb,
                                             float* __restrict__ out,
                                             float* __restrict__ lg_scratch,
                                             int bs, int lane) {
    const int m  = lane & 31;
    const int hi = lane >> 5;
    const bf16x8* w8 = reinterpret_cast<const bf16x8*>(wef_lds);

    float part[16];
    #pragma unroll
    for (int r = 0; r < 16; ++r) part[r] = 0.f;

    #pragma unroll 1
    for (int nj = 0; nj < NJ; ++nj) {
        f32x16 acc;
        #pragma unroll
        for (int r = 0; r < 16; ++r) acc[r] = 0.f;
        #pragma unroll
        for (int kk = 0; kk < 16; ++kk)
            acc = __builtin_amdgcn_mfma_f32_32x32x16_bf16(
                      A[kk], w8[(nj * 16 + kk) * 64 + lane], acc, 0, 0, 0);
        const float ha  = hatt_lds[nj * 32 + m];
        const float wsa = ws_lds[nj * 32 + m];
        #pragma unroll
        for (int r = 0; r < 16; ++r)
            part[r] = fmaf(tanh_fast(acc[r] + ha), wsa, part[r]);
    }

    #pragma unroll
    for (int r = 0; r < 16; ++r) {
        float v = part[r];
        v += __shfl_xor(v, 1);  v += __shfl_xor(v, 2);  v += __shfl_xor(v, 4);
        v += __shfl_xor(v, 8);  v += __shfl_xor(v, 16);
        part[r] = v;
    }
    if (m == 0) {
        #pragma unroll
        for (int r = 0; r < 16; ++r)
            lg_scratch[(r & 3) + 8 * (r >> 2) + 4 * hi] = part[r];
    }
    // same-wave LDS RAW: compiler inserts lgkmcnt wait

    float mx = -1e30f;
    #pragma unroll
    for (int e = 0; e < NE; ++e) mx = fmaxf(mx, lg_scratch[e]);

    const float4* eb4 = reinterpret_cast<const float4*>(eb);
    float wsum = 0.f;
    float4 o = make_float4(0.f, 0.f, 0.f, 0.f);
    #pragma unroll
    for (int e = 0; e < NE; ++e) {
        float w = __expf(lg_scratch[e] - mx);
        wsum += w;
        float4 v = eb4[e * 64 + lane];
        o.x = fmaf(w, v.x, o.x); o.y = fmaf(w, v.y, o.y);
        o.z = fmaf(w, v.z, o.z); o.w = fmaf(w, v.w, o.w);
    }
    const float inv = __builtin_amdgcn_rcpf(wsum);
    float4 res = make_float4(o.x * inv, o.y * inv, o.z * inv, o.w * inv);
    reinterpret_cast<float4*>(out)[(size_t)bs * 64 + lane] = res;
}

// ---- main: 8-wave blocks, wef in LDS, 2 tiles/wave, BATCHED tile loads ----
// The round-13 limiter: compiler interleaved load->cvt (2-4 loads in flight/
// wave -> 1.7 TB/s). Here each tile's 32 float4 loads are issued as one batch
// into u[32] (sched_barrier-fenced), and tile1's batch is in flight during
// tile0's MFMA/tanh phase (T14 issue-early/consume-late).
__global__ __launch_bounds__(512) void entatt_main(const float* __restrict__ ent,
                                                   const __bf16* __restrict__ wef,
                                                   const float* __restrict__ hattw,
                                                   const float* __restrict__ Ws,
                                                   float* __restrict__ out) {
    const int t    = threadIdx.x;
    const int lane = t & 63;
    const int wid  = t >> 6;            // 0..7
    const int g    = blockIdx.x;        // 0..255
    const int bs0  = g * 16 + wid * 2;  // this wave: bs0, bs0+1
    const int b    = g >> 5;            // 32 blocks per batch

    __shared__ __bf16 wef_lds[NJ * 16 * 512];   // 112 KB
    __shared__ float  hatt_lds[DAP];
    __shared__ float  ws_lds[DAP];
    __shared__ float  lg_lds[8][NE];

    // ---- stage full wef -> LDS (coalesced 16B; 14 float4 per thread) ----
    {
        const float4* s4 = reinterpret_cast<const float4*>(wef);
        float4* d4 = reinterpret_cast<float4*>(wef_lds);
        #pragma unroll
        for (int i = 0; i < 14; ++i) d4[t + i * 512] = s4[t + i * 512];
    }
    if (t < DAP) {
        hatt_lds[t] = hattw[b * DAP + t];
        ws_lds[t]   = (t < DA) ? Ws[t] : 0.f;
    }

    __syncthreads();   // staging drains here (L3-hot, cheap)

    const int m  = lane & 31;
    const int hi = lane >> 5;
    const float* e0 = ent + (size_t)bs0 * (NE * DE);
    const float* e1 = e0 + NE * DE;

    // ---- tile 0: issue ALL 32 loads as one batch ----
    float4 u[32];
    #pragma unroll
    for (int kk = 0; kk < 16; ++kk) {
        const float* p = e0 + m * DE + kk * 16 + hi * 4;
        u[2 * kk]     = *reinterpret_cast<const float4*>(p);
        u[2 * kk + 1] = *reinterpret_cast<const float4*>(p + 8);
    }
    __builtin_amdgcn_sched_barrier(0);   // keep the batch together

    // ---- convert tile 0 (waits on its loads; frees u) ----
    bf16x8 A0[16];
    #pragma unroll
    for (int kk = 0; kk < 16; ++kk) {
        float4 a = u[2 * kk], c = u[2 * kk + 1];
        bf16x8 v = { (__bf16)a.x, (__bf16)a.y, (__bf16)a.z, (__bf16)a.w,
                     (__bf16)c.x, (__bf16)c.y, (__bf16)c.z, (__bf16)c.w };
        A0[kk] = v;
    }

    // ---- tile 1: issue ALL 32 loads (in flight across tile-0 compute) ----
    float4 v1[32];
    #pragma unroll
    for (int kk = 0; kk < 16; ++kk) {
        const float* p = e1 + m * DE + kk * 16 + hi * 4;
        v1[2 * kk]     = *reinterpret_cast<const float4*>(p);
        v1[2 * kk + 1] = *reinterpret_cast<const float4*>(p + 8);
    }
    __builtin_amdgcn_sched_barrier(0);   // loads stay above, MFMA below

    // ---- tile 0: MFMA + logits + softmax + epilogue (L2-hot re-read) ----
    compute_tile(A0, wef_lds, hatt_lds, ws_lds, e0, out, lg_lds[wid], bs0, lane);

    // ---- convert tile 1 (waits on its loads) ----
    bf16x8 A1[16];
    #pragma unroll
    for (int kk = 0; kk < 16; ++kk) {
        float4 a = v1[2 * kk], c = v1[2 * kk + 1];
        bf16x8 v = { (__bf16)a.x, (__bf16)a.y, (__bf16)a.z, (__bf16)a.w,
                     (__bf16)c.x, (__bf16)c.y, (__bf16)c.z, (__bf16)c.w };
        A1[kk] = v;
    }
    __builtin_amdgcn_sched_barrier(0);

    compute_tile(A1, wef_lds, hatt_lds, ws_lds, e1, out, lg_lds[wid], bs0 + 1, lane);
}

extern "C" void kernel_launch(void* const* d_in, const int* in_sizes, int n_in,
                              void* d_out, int out_size, void* d_ws, size_t ws_size,
                              hipStream_t stream) {
    const float* cxt = (const float*)d_in[0];
    const float* ent = (const float*)d_in[1];
    const float* We  = (const float*)d_in[2];
    const float* Wh  = (const float*)d_in[3];
    const float* Ws  = (const float*)d_in[4];
    float* out = (float*)d_out;

    float*  psum  = (float*)d_ws;                       // 512*512 f32 = 1 MB
    float*  hattw = psum + 512 * DH;                    // 8*224 f32
    __bf16* wef   = (__bf16*)(hattw + NB * DAP);        // 7*16*512 bf16 = 112 KB

    hipLaunchKernelGGL(wef_build, dim3(NJ * 16), dim3(64), 0, stream, We, wef);
    hipLaunchKernelGGL(cmean_partial, dim3(512), dim3(256), 0, stream, cxt, psum);
    hipLaunchKernelGGL(hatt_from_psum, dim3(NB), dim3(256), 0, stream, psum, Wh, hattw);
    hipLaunchKernelGGL(entatt_main, dim3(256), dim3(512), 0, stream,
                       ent, wef, hattw, Ws, out);
}